// Round 5
// baseline (4431.812 us; speedup 1.0000x reference)
//
#include <hip/hip_runtime.h>
#include <stdint.h>

// Resonator network, b=1024 f=4 v=64 d=2048, 100 iterations.
// All values +-1 -> exact bit arithmetic. Round 5: round-4 structure
// (8 waves/block, wave=(factor j, half h), redundant phase B, phase C
// halved per wave with 16 cbT columns in registers) with the spill fixed:
// __launch_bounds__(512,2) -> VGPR cap >=128 (r4's (512,4) forced cap 64
// and spilled col[]). RING extended to 32 (anti-periods up to 62).

#define NB 1024
#define NF 4
#define ND 2048
#define NW 32            // ND/64 words per row
#define ITERS 100
#define RING 32
#define RMASK 31

#define OFF_OUT  (NB*NF*ND)
#define OFF_MS   (OFF_OUT + NB*NF)
#define OFF_CONV (OFF_MS + NB*NF)

typedef unsigned long long u64;

__device__ __forceinline__ u64 rotl64v(u64 x, int r) {
    r &= 63;
    return r ? ((x << r) | (x >> (64 - r))) : x;
}

// Pack codebooks (f,v,d) +-1 floats into two bit layouts in d_ws:
//  cbB[(j*32+w)*64 + v] : row bits, bit l = sign of cb[j,v,w*64+l]
//  cbT[j*2048 + d]      : column mask, bit v = sign of cb[j,v,d]
__global__ void pack_cb_kernel(const float* __restrict__ cb,
                               u64* __restrict__ cbB, u64* __restrict__ cbT) {
    const int lane = threadIdx.x & 63;
    const int gw   = (blockIdx.x * (blockDim.x >> 6)) + (threadIdx.x >> 6);
    const int nw   = (gridDim.x * blockDim.x) >> 6;
    for (int idx = gw; idx < NF * 64 * NW; idx += nw) {
        const int j = idx >> 11, v = (idx >> 5) & 63, w = idx & 31;
        const float x = cb[(((j << 6) | v) << 11) + (w << 6) + lane];
        const u64 m = __ballot(x < 0.0f);
        if (lane == 0) cbB[(((j << 5) | w) << 6) | v] = m;
    }
    for (int idx = gw; idx < NF * ND; idx += nw) {
        const int j = idx >> 11, d = idx & 2047;
        const float x = cb[(((j << 6) | lane) << 11) + d];
        const u64 m = __ballot(x < 0.0f);
        if (lane == 0) cbT[idx] = m;
    }
}

__global__ __launch_bounds__(512, 2) void resonator_kernel(
    const float* __restrict__ inp, const float* __restrict__ est_init,
    const u64* __restrict__ cbB, const u64* __restrict__ cbT,
    float* __restrict__ out) {
    __shared__ u64 s_hist[RING][NF][NW];   // est ring, 32 KB
    __shared__ u64 s_inp[NW];
    __shared__ u64 s_ne[NF][NW];
    __shared__ u64 s_hp[8][2];             // per-wave partial hash
    __shared__ u64 s_hring[RING][2];       // combined 128b hash ring
    __shared__ int s_ok[8];

    const int b    = blockIdx.x;
    const int tid  = threadIdx.x;
    const int wid  = tid >> 6;       // 0..7
    const int lane = tid & 63;
    const int j    = wid & 3;        // factor
    const int h    = wid >> 2;       // half
    const int w0   = h << 4;         // my phase-C word base

    const u64* cbBj = cbB + (j << 11);
    const u64* cbTj = cbT + (j << 11);

    // ---- iteration-invariant: my 16 cbT columns in registers ----
    u64 col[16];
    uint32_t colbp[4] = {0u, 0u, 0u, 0u};
    #pragma unroll
    for (int k = 0; k < 16; ++k) {
        col[k] = cbTj[((w0 + k) << 6) + lane];
        colbp[k >> 2] |= ((uint32_t)__popcll(col[k])) << ((k & 3) * 8);
    }

    // ---- pack input (4 words/wave) + est_0 (own 16 words) with hash ----
    #pragma unroll
    for (int k = 0; k < 4; ++k) {
        const int w = (wid << 2) + k;
        const u64 m = __ballot(inp[(b << 11) + (w << 6) + lane] < 0.0f);
        if (lane == 0) s_inp[w] = m;
    }
    {
        u64 hx = 0, ha = 0;
        #pragma unroll
        for (int k = 0; k < 16; ++k) {
            const int w = w0 + k;
            const u64 m = __ballot(
                est_init[(((b << 2) | j) << 11) + (w << 6) + lane] < 0.0f);
            if (lane == 0) s_hist[0][j][w] = m;
            const u64 rm = rotl64v(m, (((j << 5) | w) * 11) & 63);
            hx ^= rm; ha += rm;
        }
        if (lane == 0) { s_hp[wid][0] = hx; s_hp[wid][1] = ha; }
    }
    __syncthreads();
    if (tid == 0) {
        u64 HX = 0, HA = 0;
        #pragma unroll
        for (int q = 0; q < 8; ++q) { HX ^= s_hp[q][0]; HA += s_hp[q][1]; }
        s_hring[0][0] = HX; s_hring[0][1] = HA;
    }

    int brk_p = 0, brk_anti = 0, brk_it = ITERS;

    for (int it = 0; it < ITERS; ++it) {
        const int cur = it & RMASK, nxt = (it + 1) & RMASK;

        if (tid < 128) {
            const int jj = tid >> 5, w = tid & 31;
            const u64 X = s_inp[w] ^ s_hist[cur][0][w] ^ s_hist[cur][1][w]
                                   ^ s_hist[cur][2][w] ^ s_hist[cur][3][w];
            s_ne[jj][w] = X ^ s_hist[cur][jj][w];
        }
        __syncthreads();                                  // B1

        // ---- phase B (redundant across h): pc_v for factor j; lane = v ----
        int pc = 0;
        #pragma unroll
        for (int w = 0; w < NW; ++w)
            pc += (int)__popcll(s_ne[j][w] ^ cbBj[(w << 6) | lane]);
        int spc = pc;
        #pragma unroll
        for (int off = 32; off > 0; off >>= 1) spc += __shfl_xor(spc, off);

        const u64 c0  = __ballot(pc & 1);
        const u64 c1  = __ballot((pc >> 1) & 1);
        const u64 c2  = __ballot((pc >> 2) & 1);
        const u64 c3  = __ballot((pc >> 3) & 1);
        const u64 c4  = __ballot((pc >> 4) & 1);
        const u64 c5  = __ballot((pc >> 5) & 1);
        const u64 c6  = __ballot((pc >> 6) & 1);
        const u64 c7  = __ballot((pc >> 7) & 1);
        const u64 c8  = __ballot((pc >> 8) & 1);
        const u64 c9  = __ballot((pc >> 9) & 1);
        const u64 c10 = __ballot((pc >> 10) & 1);
        const u64 c11 = __ballot((pc >> 11) & 1);
        const int base = 131072 - 2 * spc;

        // ---- phase C: my 16 words; lane = d%64 ----
        u64 hx = 0, ha = 0;
        #pragma unroll
        for (int k = 0; k < 16; ++k) {
            const u64 cw = col[k];
            int t = base - ((int)((colbp[k >> 2] >> ((k & 3) * 8)) & 255u) << 12);
            t += (int)__popcll(c0  & cw) << 2;
            t += (int)__popcll(c1  & cw) << 3;
            t += (int)__popcll(c2  & cw) << 4;
            t += (int)__popcll(c3  & cw) << 5;
            t += (int)__popcll(c4  & cw) << 6;
            t += (int)__popcll(c5  & cw) << 7;
            t += (int)__popcll(c6  & cw) << 8;
            t += (int)__popcll(c7  & cw) << 9;
            t += (int)__popcll(c8  & cw) << 10;
            t += (int)__popcll(c9  & cw) << 11;
            t += (int)__popcll(c10 & cw) << 12;
            t += (int)__popcll(c11 & cw) << 13;
            const u64 nww = __ballot(t < 0);
            if (lane == 0) s_hist[nxt][j][w0 + k] = nww;
            const u64 rm = rotl64v(nww, (((j << 5) | (w0 + k)) * 11) & 63);
            hx ^= rm; ha += rm;
        }
        if (lane == 0) { s_hp[wid][0] = hx; s_hp[wid][1] = ha; }
        __syncthreads();                                  // B2

        // ---- hash combine + ring scan (uniform in every thread) ----
        u64 HX = 0, HA = 0;
        #pragma unroll
        for (int q = 0; q < 8; ++q) { HX ^= s_hp[q][0]; HA += s_hp[q][1]; }
        if (tid == 0) { s_hring[nxt][0] = HX; s_hring[nxt][1] = HA; }
        const u64 HAa = (u64)0 - 128ull - HA;  // hash of complemented state
        u64 maskL = 0;                          // bit p: period p ; bit p+32: anti
        const int pmax = (it + 1) < (RING - 1) ? (it + 1) : (RING - 1);
        for (int p = 1; p <= pmax; ++p) {
            const u64 rx = s_hring[(it + 1 - p) & RMASK][0];
            const u64 ra = s_hring[(it + 1 - p) & RMASK][1];
            if (rx == HX && ra == HA)  maskL |= (1ull << p);
            if (rx == HX && ra == HAa) maskL |= (1ull << (p + 32));
        }

        if (maskL) {
            int fp = 0, fa = 0;
            for (int p = 1; p <= pmax && !fp; ++p) {
                for (int a2 = 0; a2 < 2 && !fp; ++a2) {
                    if (!((maskL >> (p + (a2 ? 32 : 0))) & 1)) continue;
                    int okl = 1;
                    if (lane < 16) {
                        const u64 wa = s_hist[nxt][j][w0 + lane];
                        u64 wb = s_hist[(it + 1 - p) & RMASK][j][w0 + lane];
                        if (a2) wb = ~wb;
                        okl = (wa == wb);
                    }
                    const u64 bal = __ballot(okl != 0);
                    if (lane == 0) s_ok[wid] = (bal == ~0ull);
                    __syncthreads();
                    int allok = 1;
                    #pragma unroll
                    for (int q2 = 0; q2 < 8; ++q2) allok &= s_ok[q2];
                    __syncthreads();
                    if (allok) { fp = p; fa = a2; }
                }
            }
            if (fp) { brk_p = fp; brk_anti = fa; brk_it = it; break; }
        }
    }

    // ---- map iterations 99/100 into the ring (orbit-aware, exact) ----
    int slot100, comp100, slot99, comp99;
    if (brk_p) {
        const int s0 = brk_it + 1 - brk_p;
        const int r1 = (ITERS - s0) % brk_p;
        const int c1 = s0 + r1, t1 = (ITERS - c1) / brk_p;
        const int r2 = (ITERS - 1 - s0) % brk_p;
        const int c2 = s0 + r2, t2 = (ITERS - 1 - c2) / brk_p;
        slot100 = c1 & RMASK; comp100 = brk_anti & (t1 & 1);
        slot99  = c2 & RMASK; comp99  = brk_anti & (t2 & 1);
    } else {
        slot100 = ITERS & RMASK;       comp100 = 0;
        slot99  = (ITERS - 1) & RMASK; comp99  = 0;
    }
    __syncthreads();

    if (h == 0) {
        // max_sims[-1] = 2048 - 2*min_v pc on ne(est_99)
        int pc9 = 0;
        #pragma unroll
        for (int w = 0; w < NW; ++w) {
            const u64 X = s_inp[w] ^ s_hist[slot99][0][w] ^ s_hist[slot99][1][w]
                                   ^ s_hist[slot99][2][w] ^ s_hist[slot99][3][w];
            pc9 += (int)__popcll(X ^ s_hist[slot99][j][w] ^ cbBj[(w << 6) | lane]);
        }
        if (comp99) pc9 = ND - pc9;
        int m9 = pc9;
        #pragma unroll
        for (int off = 32; off > 0; off >>= 1) {
            const int a1 = __shfl_xor(m9, off);
            m9 = m9 < a1 ? m9 : a1;
        }
        // outcome: argmax_v |sim(est_100, cb)| (|.| complement-invariant)
        int pcO = 0;
        #pragma unroll
        for (int w = 0; w < NW; ++w)
            pcO += (int)__popcll(s_hist[slot100][j][w] ^ cbBj[(w << 6) | lane]);
        const int simF = ND - (pcO << 1);
        const int aF   = simF < 0 ? -simF : simF;
        int key = (aF << 6) | (63 - lane);
        #pragma unroll
        for (int off = 32; off > 0; off >>= 1) {
            const int t1 = __shfl_xor(key, off);
            key = key > t1 ? key : t1;
        }
        if (lane == 0) {
            out[OFF_OUT + (b << 2) + j] = (float)(63 - (key & 63));
            out[OFF_MS  + (b << 2) + j] = (float)(ND - 2 * m9);
        }
    }

    // ---- unpack est_100 ----
    const u64 cmask = comp100 ? ~0ull : 0ull;
    #pragma unroll
    for (int k = 0; k < 16; ++k) {
        const int idx = tid + (k << 9);        // 0..8191
        const int jj = idx >> 11, d = idx & 2047;
        const u64 wrd = s_hist[slot100][jj][d >> 6] ^ cmask;
        out[(b << 13) + idx] = ((wrd >> (d & 63)) & 1) ? -1.0f : 1.0f;
    }
    if (b == 0 && tid == 0) out[OFF_CONV] = 99.0f;
}

extern "C" void kernel_launch(void* const* d_in, const int* in_sizes, int n_in,
                              void* d_out, int out_size, void* d_ws, size_t ws_size,
                              hipStream_t stream) {
    const float* inp  = (const float*)d_in[0];
    const float* est0 = (const float*)d_in[1];
    const float* cb   = (const float*)d_in[2];
    float* out = (float*)d_out;
    u64* cbB = (u64*)d_ws;                 // 8192 words
    u64* cbT = cbB + NF * 64 * NW;         // 8192 words (128 KB of ws total)

    pack_cb_kernel<<<64, 256, 0, stream>>>(cb, cbB, cbT);
    resonator_kernel<<<NB, 512, 0, stream>>>(inp, est0, cbB, cbT, out);
}

// Round 6
// 2000.422 us; speedup vs baseline: 2.2154x; 2.2154x over previous
//
#include <hip/hip_runtime.h>
#include <stdint.h>

// Resonator network, b=1024 f=4 v=64 d=2048, 100 iterations.
// All values +-1 -> exact bit arithmetic. Round 6: r1's 4-wave structure,
// instruction-dieted. Measured lesson (r1..r5): early exit rarely fires
// (chaotic dynamics), so total work ~ 1024x100 iters; the lever is
// inst/iteration. Changes: adaptive 8/12-plane phase C (min-offset, exact),
// hash machinery dropped (period<=2 check only, 10-inst post-pass),
// 1 barrier/iter, free max_sim (= 2048-2*min pc).

#define NB 1024
#define NF 4
#define ND 2048
#define NW 32            // ND/64 words per row
#define ITERS 100

#define OFF_OUT  (NB*NF*ND)
#define OFF_MS   (OFF_OUT + NB*NF)
#define OFF_CONV (OFF_MS + NB*NF)

typedef unsigned long long u64;

// Pack codebooks (f,v,d) +-1 floats into two bit layouts in d_ws:
//  cbB[(j*32+w)*64 + v] : row bits, bit l = sign of cb[j,v,w*64+l]
//  cbT[j*2048 + d]      : column mask, bit v = sign of cb[j,v,d]
__global__ void pack_cb_kernel(const float* __restrict__ cb,
                               u64* __restrict__ cbB, u64* __restrict__ cbT) {
    const int lane = threadIdx.x & 63;
    const int gw   = (blockIdx.x * (blockDim.x >> 6)) + (threadIdx.x >> 6);
    const int nw   = (gridDim.x * blockDim.x) >> 6;
    for (int idx = gw; idx < NF * 64 * NW; idx += nw) {
        const int j = idx >> 11, v = (idx >> 5) & 63, w = idx & 31;
        const float x = cb[(((j << 6) | v) << 11) + (w << 6) + lane];
        const u64 m = __ballot(x < 0.0f);
        if (lane == 0) cbB[(((j << 5) | w) << 6) | v] = m;
    }
    for (int idx = gw; idx < NF * ND; idx += nw) {
        const int j = idx >> 11, d = idx & 2047;
        const float x = cb[(((j << 6) | lane) << 11) + d];
        const u64 m = __ballot(x < 0.0f);
        if (lane == 0) cbT[idx] = m;
    }
}

__global__ __launch_bounds__(256, 4) void resonator_kernel(
    const float* __restrict__ inp, const float* __restrict__ est_init,
    const u64* __restrict__ cbB, const u64* __restrict__ cbT,
    float* __restrict__ out) {
    __shared__ u64 s_hist[4][NF][NW];   // est ring (4 slots), 4 KB
    __shared__ u64 s_inp[NW];
    __shared__ u64 s_ne[NF][NW];        // touched only by its own wave
    __shared__ int s_conv[NF];

    const int b    = blockIdx.x;
    const int tid  = threadIdx.x;
    const int j    = tid >> 6;      // wave = factor
    const int lane = tid & 63;

    const u64* cbBj = cbB + (j << 11);
    const u64* cbTj = cbT + (j << 11);

    // ---- pack input (8 words/wave) + est_0 (own factor) ----
    #pragma unroll
    for (int k = 0; k < 8; ++k) {
        const int w = (j << 3) + k;
        const u64 m = __ballot(inp[(b << 11) + (w << 6) + lane] < 0.0f);
        if (lane == 0) s_inp[w] = m;
    }
    #pragma unroll 4
    for (int w = 0; w < NW; ++w) {
        const u64 m = __ballot(
            est_init[(((b << 2) | j) << 11) + (w << 6) + lane] < 0.0f);
        if (lane == 0) s_hist[0][j][w] = m;
    }
    __syncthreads();

    int m_last = 0, m_prev = 0, final_slot = 0;

    for (int it = 0; it < ITERS; ++it) {
        const int cur = it & 3, nxt = (it + 1) & 3, prv = (it + 3) & 3;

        // ne for own factor (own-wave LDS only -> no barrier needed)
        if (lane < NW) {
            const u64 X = s_inp[lane]
                        ^ s_hist[cur][0][lane] ^ s_hist[cur][1][lane]
                        ^ s_hist[cur][2][lane] ^ s_hist[cur][3][lane];
            s_ne[j][lane] = X ^ s_hist[cur][j][lane];
        }

        // ---- phase B: pc_v; lane = v ----
        int pc = 0;
        #pragma unroll
        for (int w = 0; w < NW; ++w)
            pc += (int)__popcll(s_ne[j][w] ^ cbBj[(w << 6) | lane]);

        int mn = pc, spc = pc;
        #pragma unroll
        for (int off = 32; off > 0; off >>= 1) {
            const int a1 = __shfl_xor(mn, off);
            const int a2 = __shfl_xor(spc, off);
            mn = mn < a1 ? mn : a1;
            spc += a2;
        }
        const int q = pc - mn;           // 0..2048
        m_prev = m_last;
        m_last = ND - 2 * mn;            // max_sim of this step, free
        const int base = 131072 - 2 * spc;
        const int cmul = 4 * mn - 4096;
        const u64 c0 = __ballot(q & 1),   c1 = __ballot(q & 2);
        const u64 c2 = __ballot(q & 4),   c3 = __ballot(q & 8);
        const u64 c4 = __ballot(q & 16),  c5 = __ballot(q & 32);
        const u64 c6 = __ballot(q & 64),  c7 = __ballot(q & 128);
        const u64 big = __ballot(q > 255);

        // ---- phase C: t_d = base + cmul*colb + 4*sum_k 2^k popc(ck&col) ----
        if (big == 0) {                  // q fits 8 bits (common, exact)
            #pragma unroll
            for (int w = 0; w < NW; ++w) {
                const u64 cw = cbTj[(w << 6) | lane];
                int t = base + cmul * (int)__popcll(cw);
                t += (int)__popcll(c0 & cw) << 2;
                t += (int)__popcll(c1 & cw) << 3;
                t += (int)__popcll(c2 & cw) << 4;
                t += (int)__popcll(c3 & cw) << 5;
                t += (int)__popcll(c4 & cw) << 6;
                t += (int)__popcll(c5 & cw) << 7;
                t += (int)__popcll(c6 & cw) << 8;
                t += (int)__popcll(c7 & cw) << 9;
                const u64 nww = __ballot(t < 0);
                if (lane == 0) s_hist[nxt][j][w] = nww;
            }
        } else {                         // rare: full 12-plane exact path
            const u64 c8  = __ballot(q & 256),  c9  = __ballot(q & 512);
            const u64 c10 = __ballot(q & 1024), c11 = __ballot(q & 2048);
            #pragma unroll
            for (int w = 0; w < NW; ++w) {
                const u64 cw = cbTj[(w << 6) | lane];
                int t = base + cmul * (int)__popcll(cw);
                t += (int)__popcll(c0  & cw) << 2;
                t += (int)__popcll(c1  & cw) << 3;
                t += (int)__popcll(c2  & cw) << 4;
                t += (int)__popcll(c3  & cw) << 5;
                t += (int)__popcll(c4  & cw) << 6;
                t += (int)__popcll(c5  & cw) << 7;
                t += (int)__popcll(c6  & cw) << 8;
                t += (int)__popcll(c7  & cw) << 9;
                t += (int)__popcll(c8  & cw) << 10;
                t += (int)__popcll(c9  & cw) << 11;
                t += (int)__popcll(c10 & cw) << 12;
                t += (int)__popcll(c11 & cw) << 13;
                const u64 nww = __ballot(t < 0);
                if (lane == 0) s_hist[nxt][j][w] = nww;
            }
        }

        // ---- period<=2 check: lanes 0-31 compare own factor's words ----
        int df1 = 0, df2 = 0;
        if (lane < NW) {
            const u64 a = s_hist[nxt][j][lane];   // own-wave writes
            df1 = (a != s_hist[cur][j][lane]);
            df2 = (a != s_hist[prv][j][lane]);    // it=0: garbage, guarded below
        }
        const u64 b1 = __ballot(df1), b2 = __ballot(df2);
        if (lane == 0) s_conv[j] = (b1 == 0 ? 1 : 0) | (b2 == 0 ? 2 : 0);
        __syncthreads();                          // the one barrier per iter

        const int fl = s_conv[0] & s_conv[1] & s_conv[2] & s_conv[3];
        final_slot = nxt;
        if (fl & 1) break;                        // fixed point
        if (it >= 1 && (fl & 2)) {                // period-2: resolve by parity
            if (((ITERS - it) & 1) == 0) { final_slot = cur; m_last = m_prev; }
            break;
        }
    }

    // ---- outcome: argmax_v |sim(est_100, cb)|, first-max tie-break ----
    int pcO = 0;
    #pragma unroll
    for (int w = 0; w < NW; ++w)
        pcO += (int)__popcll(s_hist[final_slot][j][w] ^ cbBj[(w << 6) | lane]);
    const int simF = ND - (pcO << 1);
    const int aF   = simF < 0 ? -simF : simF;
    int key = (aF << 6) | (63 - lane);
    #pragma unroll
    for (int off = 32; off > 0; off >>= 1) {
        const int t1 = __shfl_xor(key, off);
        key = key > t1 ? key : t1;
    }
    if (lane == 0) {
        out[OFF_OUT + (b << 2) + j] = (float)(63 - (key & 63));
        out[OFF_MS  + (b << 2) + j] = (float)m_last;
    }

    // ---- unpack est_100 ----
    #pragma unroll 4
    for (int k = 0; k < 32; ++k) {
        const int idx = tid + (k << 8);        // 0..8191
        const int jj = idx >> 11, d = idx & 2047;
        const u64 wrd = s_hist[final_slot][jj][d >> 6];
        out[(b << 13) + idx] = ((wrd >> (d & 63)) & 1) ? -1.0f : 1.0f;
    }
    if (b == 0 && tid == 0) out[OFF_CONV] = 99.0f;
}

extern "C" void kernel_launch(void* const* d_in, const int* in_sizes, int n_in,
                              void* d_out, int out_size, void* d_ws, size_t ws_size,
                              hipStream_t stream) {
    const float* inp  = (const float*)d_in[0];
    const float* est0 = (const float*)d_in[1];
    const float* cb   = (const float*)d_in[2];
    float* out = (float*)d_out;
    u64* cbB = (u64*)d_ws;                 // 8192 words
    u64* cbT = cbB + NF * 64 * NW;         // 8192 words (128 KB of ws total)

    pack_cb_kernel<<<64, 256, 0, stream>>>(cb, cbB, cbT);
    resonator_kernel<<<NB, 256, 0, stream>>>(inp, est0, cbB, cbT, out);
}